// Round 2
// 367.828 us; speedup vs baseline: 1.0636x; 1.0636x over previous
//
#include <hip/hip_runtime.h>

#define B_SZ 8
#define N_SZ 4096
#define M_SZ 2048
#define D_SZ 512

typedef __attribute__((ext_vector_type(8))) short bf16x8;
typedef __attribute__((ext_vector_type(4))) float f32x4;
typedef __attribute__((address_space(1))) const void* gptr1;
typedef __attribute__((address_space(3))) void* lptr3;

__device__ __forceinline__ unsigned short f2bf(float x) {
    unsigned int u = __builtin_bit_cast(unsigned int, x);
    u += 0x7fffu + ((u >> 16) & 1u);
    return (unsigned short)(u >> 16);
}
__device__ __forceinline__ float bf2f(unsigned short u) {
    unsigned int x = ((unsigned int)u) << 16;
    return __builtin_bit_cast(float, x);
}

__device__ __forceinline__ void vmcnt0() { asm volatile("s_waitcnt vmcnt(0)" ::: "memory"); }
__device__ __forceinline__ void vmcnt3() { asm volatile("s_waitcnt vmcnt(3)" ::: "memory"); }
__device__ __forceinline__ void vmcnt4() { asm volatile("s_waitcnt vmcnt(4)" ::: "memory"); }
template<int BN> __device__ __forceinline__ void vmcnt_steady() {
    if constexpr (BN == 256) vmcnt4(); else vmcnt3();
}

// ---------- old 128x128 B^T GEMM mainloop (kept for gemm1) ----------
__device__ __forceinline__ void bt_mainloop(
    const unsigned short* __restrict__ A, const unsigned short* __restrict__ Bt,
    int lda, int ldb, int rowBase, int colBase, int K,
    unsigned short* As, unsigned short* Bs, f32x4 acc[4][4])
{
    const int tid  = threadIdx.x;
    const int lane = tid & 63;
    const int w    = tid >> 6;
    const int wr   = (w >> 1) * 64;
    const int wc   = (w & 1) * 64;
    const int lr   = lane & 15;
    const int kq   = lane >> 4;

    const int srow0 = w * 16 + (lane >> 2);
    const int skk   = (lane & 3) * 8;

    for (int k0 = 0; k0 < K; k0 += 32) {
#pragma unroll
        for (int j = 0; j < 2; ++j) {
            const unsigned short* ga = A  + (size_t)(rowBase + srow0 + j * 64) * lda + (k0 + skk);
            const unsigned short* gb = Bt + (size_t)(colBase + srow0 + j * 64) * ldb + (k0 + skk);
            __builtin_amdgcn_global_load_lds((gptr1)ga, (lptr3)(As + (j * 4 + w) * 512), 16, 0, 0);
            __builtin_amdgcn_global_load_lds((gptr1)gb, (lptr3)(Bs + (j * 4 + w) * 512), 16, 0, 0);
        }
        asm volatile("s_waitcnt vmcnt(0)" ::: "memory");
        __syncthreads();

        bf16x8 af[4], bq[4];
#pragma unroll
        for (int i = 0; i < 4; ++i) {
            af[i] = *(const bf16x8*)(As + (wr + i * 16 + lr) * 32 + kq * 8);
            bq[i] = *(const bf16x8*)(Bs + (wc + i * 16 + lr) * 32 + kq * 8);
        }
#pragma unroll
        for (int mi = 0; mi < 4; ++mi)
#pragma unroll
            for (int ni = 0; ni < 4; ++ni)
                acc[mi][ni] = __builtin_amdgcn_mfma_f32_16x16x32_bf16(af[mi], bq[ni], acc[mi][ni], 0, 0, 0);
        __syncthreads();
    }
}

// ---------- 8-phase 256-wide mainloop machinery ----------
// Stage one half-tile (NROWS x 64 k-elems, bf16) global -> LDS, with the k-slot
// XOR swizzle applied on the GLOBAL side (global_load_lds dest must be linear).
// LDS layout: row-major [NROWS][64] bf16 (128 B rows); 16B slot s of row r holds
// global k-slot s ^ (r & 7).
template<int NROWS>
__device__ __forceinline__ void stage_half(
    const unsigned short* __restrict__ G, int ld, int grow0, int k0,
    unsigned short* lds, int tid)
{
    const int w = tid >> 6, l = tid & 63;
#pragma unroll
    for (int c = 0; c < NROWS / 64; ++c) {
        const int idx  = (c * 8 + w) * 64 + l;      // 0 .. NROWS*8-1
        const int row  = idx >> 3;                  // local row
        const int slot = (idx & 7) ^ (row & 7);     // pre-swizzled global k-slot
        const unsigned short* ga = G + (size_t)(grow0 + row) * ld + (k0 + slot * 8);
        __builtin_amdgcn_global_load_lds((gptr1)ga, (lptr3)(lds + (c * 8 + w) * 512), 16, 0, 0);
    }
}

// One phase: ds-read frags for (A-half QM, B-half QN) of buffer BUF, issue staging,
// barrier, MFMA cluster under setprio, optional counted vmcnt, barrier.
// Row mapping makes each phase read EXACTLY one A-half and one B-half globally:
//   A row = QM*128 + (w>>2)*64 + mi*16 + lr     (whole block: QM half only)
//   B row = QN*(BN/2) + (w&3)*(BN/8) + ni*16 + lr
#define PHASE(BUF, QM, QN, STAGES, TAIL)                                              \
  {                                                                                   \
    const unsigned short* Ab = As + (BUF) * (256 * 64);                               \
    const unsigned short* Bb = Bs + (BUF) * (BN * 64);                                \
    bf16x8 af[4][2], bq[NF2][2];                                                      \
    _Pragma("unroll") for (int mi = 0; mi < 4; ++mi)                                  \
      _Pragma("unroll") for (int ks = 0; ks < 2; ++ks) {                              \
        const int row = (QM) * 128 + wrow + mi * 16 + lr;                             \
        af[mi][ks] = *(const bf16x8*)(Ab + row * 64 + (((ks * 4 + kq) ^ (row & 7)) * 8)); \
      }                                                                               \
    _Pragma("unroll") for (int ni = 0; ni < NF2; ++ni)                                \
      _Pragma("unroll") for (int ks = 0; ks < 2; ++ks) {                              \
        const int row = (QN) * (BN / 2) + wcol + ni * 16 + lr;                        \
        bq[ni][ks] = *(const bf16x8*)(Bb + row * 64 + (((ks * 4 + kq) ^ (row & 7)) * 8)); \
      }                                                                               \
    STAGES;                                                                           \
    __builtin_amdgcn_s_barrier();                                                     \
    __builtin_amdgcn_s_setprio(1);                                                    \
    _Pragma("unroll") for (int mi = 0; mi < 4; ++mi)                                  \
      _Pragma("unroll") for (int ni = 0; ni < NF2; ++ni)                              \
        _Pragma("unroll") for (int ks = 0; ks < 2; ++ks)                              \
          acc[(QM) * 4 + mi][(QN) * NF2 + ni] = __builtin_amdgcn_mfma_f32_16x16x32_bf16( \
              af[mi][ks], bq[ni][ks], acc[(QM) * 4 + mi][(QN) * NF2 + ni], 0, 0, 0);  \
    __builtin_amdgcn_s_setprio(0);                                                    \
    TAIL;                                                                             \
    __builtin_amdgcn_s_barrier();                                                     \
  }

// C[rowBase:+256, colBase:+BN] += A[256 x K] * Bt[BN x K]^T, 512 threads / 8 waves.
// Race-free stage ring (each region's last reader finishes a barrier before the
// stage that overwrites it; counted vmcnt covers each half 3-5 phases later):
//   buf0 window: PH1(A0,B0-read) stage buf1.A1 | PH2(A0,B1) stage buf1.B1
//                PH3(A1,B0) stage buf0'.A0     | PH4(A1,B1) stage buf0'.B0 +vmcnt(4)->buf1 ready
//   buf1 window: PH5(A0,B0) stage buf0'.A1     | PH6(A0,B1) stage buf0'.B1
//                PH7(A1,B0) stage buf1'.A0     | PH8(A1,B1) stage buf1'.B0 +vmcnt(4)->buf0' ready
template<int BN>
__device__ __forceinline__ void mainloop8(
    const unsigned short* __restrict__ A, const unsigned short* __restrict__ Bt,
    int lda, int ldb, int rowBase, int colBase, int K,
    unsigned short* As, unsigned short* Bs, f32x4 (&acc)[8][BN / 64])
{
    constexpr int NF2  = BN / 128;      // n-frags per phase (2 or 1)
    constexpr int BNH  = BN / 2;
    constexpr int ABUF = 256 * 64, AH = 128 * 64;
    constexpr int BBUF = BN * 64,  BH = BNH * 64;
    const int tid = threadIdx.x, lane = tid & 63, w = tid >> 6;
    const int wrow = (w >> 2) * 64;
    const int wcol = (w & 3) * (BN / 8);
    const int lr = lane & 15, kq = lane >> 4;
    const int niter = K >> 7;

    // prologue: buf0 = kt0 (4 halves), buf1 = kt1 (A0,B0); wait buf0, keep buf1 in flight
    stage_half<128>(A,  lda, rowBase,       0,  As,        tid);
    stage_half<BNH>(Bt, ldb, colBase,       0,  Bs,        tid);
    stage_half<128>(A,  lda, rowBase + 128, 0,  As + AH,   tid);
    stage_half<BNH>(Bt, ldb, colBase + BNH, 0,  Bs + BH,   tid);
    stage_half<128>(A,  lda, rowBase,       64, As + ABUF, tid);
    stage_half<BNH>(Bt, ldb, colBase,       64, Bs + BBUF, tid);
    vmcnt_steady<BN>();
    __builtin_amdgcn_s_barrier();

    for (int I = 0; I < niter; ++I) {
        const bool nl = (I + 1 < niter);
        const int ke = I << 7;
        PHASE(0, 0, 0, { stage_half<128>(A,  lda, rowBase + 128, ke + 64,  As + ABUF + AH, tid); }, {});
        PHASE(0, 0, 1, { stage_half<BNH>(Bt, ldb, colBase + BNH, ke + 64,  Bs + BBUF + BH, tid); }, {});
        PHASE(0, 1, 0, { if (nl) stage_half<128>(A,  lda, rowBase,       ke + 128, As,      tid); }, {});
        PHASE(0, 1, 1, { if (nl) stage_half<BNH>(Bt, ldb, colBase,       ke + 128, Bs,      tid); },
                       { if (nl) vmcnt_steady<BN>(); else vmcnt0(); });
        PHASE(1, 0, 0, { if (nl) stage_half<128>(A,  lda, rowBase + 128, ke + 128, As + AH, tid); }, {});
        PHASE(1, 0, 1, { if (nl) stage_half<BNH>(Bt, ldb, colBase + BNH, ke + 128, Bs + BH, tid); }, {});
        PHASE(1, 1, 0, { if (nl) stage_half<128>(A,  lda, rowBase,       ke + 192, As + ABUF, tid); }, {});
        PHASE(1, 1, 1, { if (nl) stage_half<BNH>(Bt, ldb, colBase,       ke + 192, Bs + BBUF, tid); },
                       { if (nl) vmcnt_steady<BN>(); else vmcnt0(); });
    }
}

// ---------- prep: normalize text[1] rows -> tn, copy t1 into out, zero L & SS ----------
__global__ __launch_bounds__(256) void prep_tn_k(
    const float* __restrict__ text, unsigned short* __restrict__ tn,
    float* __restrict__ out, float* __restrict__ L, float* __restrict__ SS)
{
    const int m = blockIdx.x;
    const int t = threadIdx.x;  // 256
    const float* t1 = text + (size_t)M_SZ * D_SZ;
    float2 v = ((const float2*)(t1 + (size_t)m * D_SZ))[t];
    float s = v.x * v.x + v.y * v.y;
#pragma unroll
    for (int off = 32; off > 0; off >>= 1) s += __shfl_down(s, off);
    __shared__ float partial[4];
    if ((t & 63) == 0) partial[t >> 6] = s;
    __syncthreads();
    float norm = sqrtf(partial[0] + partial[1] + partial[2] + partial[3]);
    norm = fmaxf(norm, 1e-8f);
    const float inv = 1.f / norm;
    ushort2 pk; pk.x = f2bf(v.x * inv); pk.y = f2bf(v.y * inv);
    ((ushort2*)(tn + (size_t)m * D_SZ))[t] = pk;
#pragma unroll
    for (int b = 0; b < B_SZ; ++b)
        ((float2*)(out + ((size_t)(b * M_SZ + m)) * (2 * D_SZ) + D_SZ))[t] = v;
    if (m < 64) L[m * 256 + t] = 0.f;
    if (m < 128) SS[m * 256 + t] = 0.f;
}

// ---------- prep: transpose W (fp32 [d][e]) -> Wt (bf16 [e][d]) ----------
__global__ __launch_bounds__(256) void prep_w_k(
    const float* __restrict__ W, unsigned short* __restrict__ Wt)
{
    const int dt = blockIdx.x, et = blockIdx.y;
    const int t = threadIdx.x;
    __shared__ unsigned short tile[64][72];
    const int rr = t >> 4;
    const int cc = (t & 15) * 4;
#pragma unroll
    for (int p = 0; p < 4; ++p) {
        const int d = p * 16 + rr;
        const float4 v = *(const float4*)(W + (size_t)(dt * 64 + d) * D_SZ + et * 64 + cc);
        tile[d][cc] = f2bf(v.x); tile[d][cc + 1] = f2bf(v.y);
        tile[d][cc + 2] = f2bf(v.z); tile[d][cc + 3] = f2bf(v.w);
    }
    __syncthreads();
#pragma unroll
    for (int p = 0; p < 4; ++p) {
        const int e = p * 16 + rr;
        ushort4 pk;
        pk.x = tile[cc][e]; pk.y = tile[cc + 1][e]; pk.z = tile[cc + 2][e]; pk.w = tile[cc + 3][e];
        *(ushort4*)(Wt + (size_t)(et * 64 + e) * D_SZ + dt * 64 + cc) = pk;
    }
}

// ---------- features fp32 -> V bf16 [b*n][d] and Vt bf16 [b][d][n] ----------
__global__ __launch_bounds__(256) void convert_feat_k(
    const float* __restrict__ feat, unsigned short* __restrict__ V,
    unsigned short* __restrict__ Vt)
{
    const int nt = blockIdx.x, dt = blockIdx.y, b = blockIdx.z;
    const int t = threadIdx.x;
    __shared__ unsigned short tile[64][72];
    const int rr = t >> 4;
    const int cc = (t & 15) * 4;
#pragma unroll
    for (int p = 0; p < 4; ++p) {
        const int r = p * 16 + rr;
        const size_t grow = (size_t)(b * N_SZ + nt * 64 + r);
        const float4 v = *(const float4*)(feat + grow * D_SZ + dt * 64 + cc);
        ushort4 pk; pk.x = f2bf(v.x); pk.y = f2bf(v.y); pk.z = f2bf(v.z); pk.w = f2bf(v.w);
        *(ushort4*)(V + grow * D_SZ + dt * 64 + cc) = pk;
        tile[r][cc] = pk.x; tile[r][cc + 1] = pk.y; tile[r][cc + 2] = pk.z; tile[r][cc + 3] = pk.w;
    }
    __syncthreads();
#pragma unroll
    for (int p = 0; p < 4; ++p) {
        const int d = p * 16 + rr;
        ushort4 pk;
        pk.x = tile[cc][d]; pk.y = tile[cc + 1][d]; pk.z = tile[cc + 2][d]; pk.w = tile[cc + 3][d];
        *(ushort4*)(Vt + ((size_t)(b * D_SZ + dt * 64 + d)) * N_SZ + nt * 64 + cc) = pk;
    }
}

// ---------- gemm1: f1b = bf16(V @ Wt^T + bias); SS[row] += sum(f1^2) ----------
__global__ __launch_bounds__(256) void gemm1_k(
    const unsigned short* __restrict__ V, const unsigned short* __restrict__ Wt,
    const float* __restrict__ bias, unsigned short* __restrict__ f1b,
    float* __restrict__ SS)
{
    __shared__ unsigned short As[128 * 32];
    __shared__ unsigned short Bs[128 * 32];
    f32x4 acc[4][4];
#pragma unroll
    for (int i = 0; i < 4; ++i)
#pragma unroll
        for (int j = 0; j < 4; ++j) acc[i][j] = (f32x4){0.f, 0.f, 0.f, 0.f};
    const int tid = threadIdx.x, lane = tid & 63, w = tid >> 6;
    const int wr = (w >> 1) * 64, wc = (w & 1) * 64, lr = lane & 15, kq = lane >> 4;

    const int rowBase = blockIdx.x * 128;
    const int colBase = blockIdx.y * 128;
    bt_mainloop(V, Wt, D_SZ, D_SZ, rowBase, colBase, D_SZ, As, Bs, acc);

#pragma unroll
    for (int mi = 0; mi < 4; ++mi) {
        const int r0 = rowBase + wr + mi * 16 + kq * 4;
        float s[4] = {0.f, 0.f, 0.f, 0.f};
#pragma unroll
        for (int ni = 0; ni < 4; ++ni) {
            const int c = colBase + wc + ni * 16 + lr;
            const float bv = bias[c];
#pragma unroll
            for (int r = 0; r < 4; ++r) {
                const float v = acc[mi][ni][r] + bv;
                f1b[(size_t)(r0 + r) * D_SZ + c] = f2bf(v);
                s[r] += v * v;
            }
        }
#pragma unroll
        for (int off = 1; off <= 8; off <<= 1)
#pragma unroll
            for (int r = 0; r < 4; ++r) s[r] += __shfl_xor(s[r], off);
        if (lr == 0) {
#pragma unroll
            for (int r = 0; r < 4; ++r) atomicAdd(&SS[r0 + r], s[r]);
        }
    }
}

// ---------- normalize: fn = bf16(f1b * rsqrt-ish(SS)) ----------
__global__ __launch_bounds__(128) void normalize_k(
    const unsigned short* __restrict__ f1b, const float* __restrict__ SS,
    unsigned short* __restrict__ fn)
{
    const int row = blockIdx.x;
    const int t = threadIdx.x;  // 128
    const float norm = fmaxf(sqrtf(SS[row]), 1e-8f);
    const float inv = 1.f / norm;
    ushort4 v = ((const ushort4*)(f1b + (size_t)row * D_SZ))[t];
    ushort4 o;
    o.x = f2bf(bf2f(v.x) * inv); o.y = f2bf(bf2f(v.y) * inv);
    o.z = f2bf(bf2f(v.z) * inv); o.w = f2bf(bf2f(v.w) * inv);
    ((ushort4*)(fn + (size_t)row * D_SZ))[t] = o;
}

// ---------- gemm2 (8-phase 256x256): sim = fn @ tn^T; E[b][m][n]=bf16(exp); L += sums ----------
__global__ __launch_bounds__(512, 1) void gemm2_k8(
    const unsigned short* __restrict__ fn, const unsigned short* __restrict__ tn,
    unsigned short* __restrict__ E, float* __restrict__ L)
{
    __shared__ unsigned short smem[65536];   // 128 KiB: staging; reused as swizzled P-tile
    unsigned short* As = smem;               // [2][256*64]
    unsigned short* Bs = smem + 32768;       // [2][256*64]
    f32x4 acc[8][4];
#pragma unroll
    for (int i = 0; i < 8; ++i)
#pragma unroll
        for (int j = 0; j < 4; ++j) acc[i][j] = (f32x4){0.f, 0.f, 0.f, 0.f};

    const int lin = blockIdx.x;              // 1024 blocks
    const int xcd = lin & 7, slot = lin >> 3;
    const int mt = slot & 7;                 // tn col-tile (inner: tn L2-resident)
    const int rt = (slot >> 3) * 8 + xcd;    // fn row-tile pinned per XCD
    const int rowBase = rt * 256;            // fn rows (b*4096 + n)
    const int colBase = mt * 256;            // tn rows (m)

    mainloop8<256>(fn, tn, D_SZ, D_SZ, rowBase, colBase, D_SZ, As, Bs, acc);
    __syncthreads();                         // mainloop drained (last iter vmcnt(0))

    const int tid = threadIdx.x, lane = tid & 63, w = tid >> 6;
    const int wrow = (w >> 2) * 64, wcol = (w & 3) * 32;
    const int lr = lane & 15, kq = lane >> 4;
    const int b = rowBase >> 12;
    const int nb0 = rowBase & 4095;

    // write exp() into swizzled P[m 256][n 256] (16B slot s of row m at s^(m&7))
    unsigned short* P = smem;
    float ps[4] = {0.f, 0.f, 0.f, 0.f};
#pragma unroll
    for (int a = 0; a < 8; ++a) {
        const int n0 = (a >> 2) * 128 + wrow + (a & 3) * 16 + kq * 4;   // local n
#pragma unroll
        for (int j = 0; j < 4; ++j) {
            const int m = (j >> 1) * 128 + wcol + (j & 1) * 16 + lr;    // local m
            const float e0 = __expf(acc[a][j][0]);
            const float e1 = __expf(acc[a][j][1]);
            const float e2 = __expf(acc[a][j][2]);
            const float e3 = __expf(acc[a][j][3]);
            ushort4 pk; pk.x = f2bf(e0); pk.y = f2bf(e1); pk.z = f2bf(e2); pk.w = f2bf(e3);
            *(ushort4*)(P + m * 256 + (((n0 >> 3) ^ (m & 7)) * 8) + (n0 & 7)) = pk;
            ps[j] += (e0 + e1) + (e2 + e3);
        }
    }
#pragma unroll
    for (int j = 0; j < 4; ++j) {
        float p = ps[j];
        p += __shfl_down(p, 16);
        p += __shfl_down(p, 32);
        const int m = (j >> 1) * 128 + wcol + (j & 1) * 16 + lr;
        if (lane < 16) atomicAdd(&L[b * M_SZ + colBase + m], p);
    }
    __syncthreads();

    // coalesced transposed store: 32 lanes cover 512 contiguous bytes along n
    unsigned short* Eb = E + (size_t)b * M_SZ * N_SZ;
#pragma unroll
    for (int c = 0; c < 16; ++c) {
        const int rm = c * 16 + (tid >> 5);
        const int ns = tid & 31;
        bf16x8 v = *(const bf16x8*)(P + rm * 256 + ((ns ^ (rm & 7)) * 8));
        *(bf16x8*)(Eb + (size_t)(colBase + rm) * N_SZ + nb0 + ns * 8) = v;
    }
}

// ---------- gemm3 (8-phase 256x128): fm = (E @ Vt^T) / L -> out left half ----------
__global__ __launch_bounds__(512, 1) void gemm3_k8(
    const unsigned short* __restrict__ E, const unsigned short* __restrict__ Vt,
    const float* __restrict__ L, float* __restrict__ out)
{
    __shared__ unsigned short smem[49152];   // 96 KiB: As 64K + Bs 32K
    unsigned short* As = smem;               // [2][256*64]
    unsigned short* Bs = smem + 32768;       // [2][128*64]
    f32x4 acc[8][2];
#pragma unroll
    for (int i = 0; i < 8; ++i)
#pragma unroll
        for (int j = 0; j < 2; ++j) acc[i][j] = (f32x4){0.f, 0.f, 0.f, 0.f};

    const int lin = blockIdx.x;              // 256 blocks
    const int mtile = lin & 7;               // E m-tile pinned per XCD (2 MiB, L2-resident)
    const int slot = lin >> 3;
    const int dt = slot & 3;                 // Vt d-tile (inner)
    const int b = slot >> 2;
    const int rowBase = mtile * 256;         // m
    const int colBase = dt * 128;            // d

    const unsigned short* Ab = E + (size_t)b * M_SZ * N_SZ;
    const unsigned short* Bb = Vt + (size_t)b * D_SZ * N_SZ;
    mainloop8<128>(Ab, Bb, N_SZ, N_SZ, rowBase, colBase, N_SZ, As, Bs, acc);

    const int tid = threadIdx.x, lane = tid & 63, w = tid >> 6;
    const int wrow = (w >> 2) * 64, wcol = (w & 3) * 16;
    const int lr = lane & 15, kq = lane >> 4;

#pragma unroll
    for (int a = 0; a < 8; ++a) {
        const int r0 = rowBase + (a >> 2) * 128 + wrow + (a & 3) * 16 + kq * 4;
        float invl[4];
#pragma unroll
        for (int r = 0; r < 4; ++r) invl[r] = 1.f / L[b * M_SZ + r0 + r];
#pragma unroll
        for (int j = 0; j < 2; ++j) {
            const int d = colBase + j * 64 + wcol + lr;
#pragma unroll
            for (int r = 0; r < 4; ++r)
                out[((size_t)(b * M_SZ + r0 + r)) * (2 * D_SZ) + d] = acc[a][j][r] * invl[r];
        }
    }
}

extern "C" void kernel_launch(void* const* d_in, const int* in_sizes, int n_in,
                              void* d_out, int out_size, void* d_ws, size_t ws_size,
                              hipStream_t stream) {
    const float* features = (const float*)d_in[0];   // [8, 4096, 512]
    const float* text     = (const float*)d_in[1];   // [2, 2048, 512]
    const float* W        = (const float*)d_in[2];   // [512, 512]
    const float* bias     = (const float*)d_in[3];   // [512]
    float* out = (float*)d_out;                      // [8, 2048, 1024]
    char* ws = (char*)d_ws;

    // workspace layout (bytes)
    unsigned short* fn  = (unsigned short*)(ws + 0);            // 32 MiB
    unsigned short* tn  = (unsigned short*)(ws + 33554432);     //  2 MiB
    unsigned short* Wt  = (unsigned short*)(ws + 35651584);     // .5 MiB
    unsigned short* V   = (unsigned short*)(ws + 36175872);     // 32 MiB
    unsigned short* Vt  = (unsigned short*)(ws + 69730304);     // 32 MiB
    float*          L   = (float*)(ws + 103284736);             // 64 KiB
    float*          SS  = (float*)(ws + 103350272);             // 128 KiB
    unsigned short* E   = (unsigned short*)(ws + 103481344);    // 128 MiB
    unsigned short* f1b = (unsigned short*)(ws + 103481344);    // 32 MiB (aliases E; dead before gemm2)

    hipLaunchKernelGGL(prep_tn_k, dim3(M_SZ), dim3(256), 0, stream, text, tn, out, L, SS);
    hipLaunchKernelGGL(prep_w_k, dim3(8, 8), dim3(256), 0, stream, W, Wt);
    hipLaunchKernelGGL(convert_feat_k, dim3(64, 8, 8), dim3(256), 0, stream, features, V, Vt);
    hipLaunchKernelGGL(gemm1_k, dim3(256, 4), dim3(256), 0, stream, V, Wt, bias, f1b, SS);
    hipLaunchKernelGGL(normalize_k, dim3(32768), dim3(128), 0, stream, f1b, SS, fn);
    hipLaunchKernelGGL(gemm2_k8, dim3(1024), dim3(512), 0, stream, fn, tn, E, L);
    hipLaunchKernelGGL(gemm3_k8, dim3(256), dim3(512), 0, stream, E, Vt, L, out);
}